// Round 3
// baseline (143.021 us; speedup 1.0000x reference)
//
#include <hip/hip_runtime.h>

#define N_NODES  50000
#define N_EDGES  600000
#define CHANNELS 128
#define HEADS    8
#define HEAD_DIM 16     // CHANNELS / HEADS
#define CAP      64     // per-node capacity; degrees ~ Poisson(12), max ~28

#define NBINS    256    // dst bins; bin = dst*NBINS/N_NODES (~196 nodes/bin)
#define CHUNK_E  1024   // edges per chunk
#define NCHUNK   ((N_EDGES + CHUNK_E - 1) / CHUNK_E)     // 586
#define SEGCAP   2816   // per-bin edge segment capacity (mean 2344, +~10 sigma)
#define NPB      200    // max nodes per bin (196) rounded up
#define BPAD     16     // bincnt padding (ints): one 64B line per bin counter

#define LOGIT_VB ((N_NODES * (CHANNELS / 8)) / 256)      // 3125 (8 channels/thread)
#define WPB      4      // waves (nodes) per block in the fused kernel

// bf16 round-to-nearest-even of an fp32 bit pattern
__device__ __forceinline__ unsigned bf16rne(float f) {
    unsigned u = __float_as_uint(f);
    return (u + 0x7FFFu + ((u >> 16) & 1u)) >> 16;
}

// ---------------------------------------------------------------------------
// A: per-node logit halves + bf16(x) sweep (8 channels per thread: 32B in,
//    16B packed-bf16 out).  Block LOGIT_VB zeroes the padded bin counters so
//    binscatter can allocate via global atomics (graph-capture safe, no
//    memset).
// R1 lesson: never scatter sub-line stores/atomics across a large region
// (27x write-amp, 9% HBM, 46us).  R3 allocation atomics are fine: 256
// line-padded addresses only.
// ---------------------------------------------------------------------------
__global__ void logit_kernel(const float* __restrict__ x,
                             const float* __restrict__ att,
                             float*          __restrict__ ls8,
                             float*          __restrict__ ld8,
                             unsigned short* __restrict__ xb,
                             int*            __restrict__ bincnt_p) {
    if (blockIdx.x == LOGIT_VB) {                // zero block
        bincnt_p[threadIdx.x * BPAD] = 0;
        return;
    }
    int gid = blockIdx.x * 256 + threadIdx.x;    // (node, 8-channel slot)
    int n  = gid >> 4;                           // 16 slots per node
    int c8 = gid & 15;
    int h  = c8 >> 1;                            // 2 slots per head
    int j8 = c8 & 1;

    const float4* xp = (const float4*)x + (size_t)gid * 2;
    float4 v0 = xp[0], v1 = xp[1];

    // packed bf16 store: 8 channels -> uint4 (16B)
    uint4 pk;
    pk.x = bf16rne(v0.x) | (bf16rne(v0.y) << 16);
    pk.y = bf16rne(v0.z) | (bf16rne(v0.w) << 16);
    pk.z = bf16rne(v1.x) | (bf16rne(v1.y) << 16);
    pk.w = bf16rne(v1.z) | (bf16rne(v1.w) << 16);
    ((uint4*)xb)[gid] = pk;

    // att row = 32 floats = 8 float4s: [a_src(4), a_dst(4)]
    const float4* att4 = (const float4*)att;
    float4 as0 = att4[h * 8 + j8 * 2],     as1 = att4[h * 8 + j8 * 2 + 1];
    float4 ad0 = att4[h * 8 + 4 + j8 * 2], ad1 = att4[h * 8 + 5 + j8 * 2];
    float ts = v0.x*as0.x + v0.y*as0.y + v0.z*as0.z + v0.w*as0.w
             + v1.x*as1.x + v1.y*as1.y + v1.z*as1.z + v1.w*as1.w;
    float td = v0.x*ad0.x + v0.y*ad0.y + v0.z*ad0.z + v0.w*ad0.w
             + v1.x*ad1.x + v1.y*ad1.y + v1.z*ad1.z + v1.w*ad1.w;
    ts += __shfl_xor(ts, 1, 2);
    td += __shfl_xor(td, 1, 2);
    if (j8 == 0) {
        ls8[n * HEADS + h] = ts;
        ld8[n * HEADS + h] = td;
    }
}

// ---------------------------------------------------------------------------
// B: binned scatter with IN-KERNEL allocation (replaces hist+scan+binscatter).
// Pass 1: LDS histogram over this chunk's 1024 edges; records+bins kept in
// registers.  Alloc: one global atomicAdd per (block,bin) on line-padded
// counters (256 parallel lines, ~150k atomics total).  Pass 2: LDS-atomic
// rank + scattered 4B record store into the bin segment.
// Within-bin order is nondeterministic across chunks — same as before
// end-to-end, since bucket_kernel re-ranks nondeterministically anyway.
// ---------------------------------------------------------------------------
__global__ void binscatter_kernel(const int* __restrict__ src,
                                  const int* __restrict__ dst,
                                  int*       __restrict__ bincnt_p,
                                  unsigned*  __restrict__ ebuf) {
    __shared__ int lh[NBINS];                    // histogram, then rank counter
    __shared__ int lbase[NBINS];
    int b = blockIdx.x;
    int t = threadIdx.x;
    lh[t] = 0;
    __syncthreads();
    int base = b * CHUNK_E;
    unsigned rec[4], bn[4];
#pragma unroll
    for (int k = 0; k < 4; ++k) {
        int e = base + t + k * 256;
        if (e < N_EDGES) {
            int d = dst[e];
            int s = src[e];
            unsigned bin = (unsigned)(d * NBINS) / N_NODES;
            bn[k]  = bin;
            rec[k] = (unsigned)s | ((unsigned)d << 16);
            atomicAdd(&lh[bin], 1);              // LDS atomic
        } else bn[k] = 0xFFFFFFFFu;
    }
    __syncthreads();
    int cnt_bin = lh[t];
    __syncthreads();
    lbase[t] = (cnt_bin > 0) ? atomicAdd(&bincnt_p[t * BPAD], cnt_bin) : 0;
    lh[t] = 0;                                   // reuse as rank counter
    __syncthreads();
#pragma unroll
    for (int k = 0; k < 4; ++k) {
        if (bn[k] != 0xFFFFFFFFu) {
            int r = atomicAdd(&lh[bn[k]], 1) + lbase[bn[k]];   // LDS atomic
            if (r < SEGCAP)
                ebuf[(size_t)bn[k] * SEGCAP + r] = rec[k];
        }
    }
}

// ---------------------------------------------------------------------------
// C: one block per bin — coalesced read of the bin's edge segment, LDS-atomic
// rank into per-node LDS rows, then one coalesced uint4 copy to the global
// bucket (replaces 600k scattered 2B stores).
// ---------------------------------------------------------------------------
__global__ void bucket_kernel(const unsigned* __restrict__ ebuf,
                              const int*      __restrict__ bincnt_p,
                              int*            __restrict__ cursor,
                              unsigned short* __restrict__ bucket) {
    __shared__ unsigned short rows[NPB * CAP];   // 25.6 KB
    __shared__ int lcnt[NPB];
    int b = blockIdx.x;
    int t = threadIdx.x;
    int n0 = (b * N_NODES + NBINS - 1) / NBINS;
    int n1 = ((b + 1) * N_NODES + NBINS - 1) / NBINS;
    int nn = n1 - n0;
    if (t < NPB) lcnt[t] = 0;
    __syncthreads();
    int cnt = min(bincnt_p[b * BPAD], SEGCAP);
    for (int i = t; i < cnt; i += 256) {
        unsigned rec = ebuf[(size_t)b * SEGCAP + i];
        int s = (int)(rec & 0xFFFFu);
        int d = (int)(rec >> 16);
        int pos = atomicAdd(&lcnt[d - n0], 1);              // LDS atomic
        if (pos < CAP) rows[(d - n0) * CAP + pos] = (unsigned short)s;
    }
    __syncthreads();
    // coalesced LDS -> global copy (slots >= count are garbage, never
    // dereferenced past cnt by the fused kernel)
    int nq = nn * (CAP * 2 / 16);                // nn * 8 uint4s
    uint4* gdst = (uint4*)(bucket + (size_t)n0 * CAP);
    const uint4* lsrc = (const uint4*)rows;
    for (int i = t; i < nq; i += 256) gdst[i] = lsrc[i];
    if (t < nn) cursor[n0 + t] = lcnt[t];
}

// ---------------------------------------------------------------------------
// Fused GAT aggregation.  One wave per node.
// Pass 1 (h=lane>>3, j=lane&7): logits in registers, 8-lane shuffle max
//   (clamped at 0 == reference's max(seg_max,0)), one exp per (edge,head)
//   -> LDS, denominator reduced in-register.  (R11-proven)
// Pass 2: FOUR edges per wave-load — uint4/lane (16B), 16 lanes = one 256B
//   bf16 row, r=lane>>4 picks the edge of the quad, l16=lane&15 the channel
//   octet.  4-slot statically-indexed uint4 window (R2: neutral vs uint2x8 —
//   kernel is at its gather/write floor — kept for lower instruction count).
//   NOTE: q[] must only ever be indexed by compile-time constants — dynamic
//   indexing spills the window (R12: 72KB LDS/block, 3.6x regression).
// Bucket slots >= cnt are uninitialized workspace: every access path is
// either `i < cnt`-guarded (pass 1) or shfl-index-clamped to < cnt (pass 2),
// so garbage is never dereferenced.
// ---------------------------------------------------------------------------
__global__ void fused_gat_kernel(const unsigned short* __restrict__ xb,
                                 const float* __restrict__ ls8,
                                 const float* __restrict__ ld8,
                                 const int*   __restrict__ cursor,
                                 const unsigned short* __restrict__ bucket,
                                 float*       __restrict__ out) {
    __shared__ float s_p[WPB * CAP * HEADS];     // 8 KB: staged softmax numerators

    int wave = threadIdx.x >> 6;
    int lane = threadIdx.x & 63;
    int n = blockIdx.x * WPB + wave;
    if (n >= N_NODES) return;
    int h = lane >> 3;                           // pass-1 head
    int j = lane & 7;
    int r   = lane >> 4;                         // pass-2: which edge of quad (0..3)
    int l16 = lane & 15;                         // pass-2: channel octet
    int h2  = l16 >> 1;                          // pass-2 head (8 channels never cross a head)

    int   cnt_raw = cursor[n];
    int   myidx   = (int)bucket[(size_t)n * CAP + lane];
    float ldst    = ld8[n * HEADS + h];
    int cnt = (cnt_raw > CAP) ? CAP : cnt_raw;

    float* sp = s_p + wave * (CAP * HEADS);

    // ---- pass 1: logits in registers, per-head max, single exp per value ----
    float av[8];
    float mymax = -1e30f;
#pragma unroll
    for (int k = 0; k < 8; ++k) {
        int i = j + 8 * k;
        av[k] = -1e30f;
        if (i < cnt) {
            int   s  = __shfl(myidx, i);
            float lg = ls8[s * HEADS + h] + ldst;
            float a  = (lg >= 0.0f) ? lg : 0.2f * lg;   // LeakyReLU(0.2)
            av[k] = a;
            mymax = fmaxf(mymax, a);
        }
    }
#pragma unroll
    for (int o = 4; o >= 1; o >>= 1) mymax = fmaxf(mymax, __shfl_xor(mymax, o, 8));
    float m = fmaxf(mymax, 0.0f);                // reference clamps seg_max at 0

    float myl = 0.0f;
#pragma unroll
    for (int k = 0; k < 8; ++k) {
        int i = j + 8 * k;
        if (i < cnt) {
            float p = __expf(av[k] - m);
            sp[i * HEADS + h] = p;               // 2-way bank aliasing only
            myl += p;
        }
    }
#pragma unroll
    for (int o = 4; o >= 1; o >>= 1) myl += __shfl_xor(myl, o, 8);

    // ---- pass 2: weighted accumulate, 4 edges/load, window 4 uint4 slots ----
#define LO16(u) __uint_as_float((u) << 16)
#define HI16(u) __uint_as_float((u) & 0xFFFF0000u)
#define LP(kq) ( ((const uint4*)(xb + (size_t)__shfl(myidx, ((4*(kq)+r) < cnt) ? (4*(kq)+r) : 0) * CHANNELS))[l16] )
    uint4 q[4];
#pragma unroll
    for (int k = 0; k < 4; ++k) q[k] = LP(k);

    float a0 = 0.f, a1 = 0.f, a2 = 0.f, a3 = 0.f;
    float a4 = 0.f, a5 = 0.f, a6 = 0.f, a7 = 0.f;
    int nquad = (cnt + 3) >> 2;
    int k = 0;
    for (; k + 2 <= nquad; k += 2) {
#pragma unroll
        for (int u = 0; u < 2; ++u) {
            int e4 = 4 * (k + u) + r;
            float p = (e4 < cnt) ? sp[e4 * HEADS + h2] : 0.0f;
            uint4 qq = q[u];
            a0 += p * LO16(qq.x);
            a1 += p * HI16(qq.x);
            a2 += p * LO16(qq.y);
            a3 += p * HI16(qq.y);
            a4 += p * LO16(qq.z);
            a5 += p * HI16(qq.z);
            a6 += p * LO16(qq.w);
            a7 += p * HI16(qq.w);
        }
        q[0] = q[2]; q[1] = q[3];
        q[2] = LP(k + 4);
        q[3] = LP(k + 5);
    }
    for (; k < nquad; ++k) {                     // tail 0..1 quads
        int e4 = 4 * k + r;
        float p = (e4 < cnt) ? sp[e4 * HEADS + h2] : 0.0f;
        uint4 qq = q[0];
        a0 += p * LO16(qq.x);
        a1 += p * HI16(qq.x);
        a2 += p * LO16(qq.y);
        a3 += p * HI16(qq.y);
        a4 += p * LO16(qq.z);
        a5 += p * HI16(qq.z);
        a6 += p * LO16(qq.w);
        a7 += p * HI16(qq.w);
        q[0] = q[1]; q[1] = q[2]; q[2] = q[3];
    }
#undef LP
#undef LO16
#undef HI16

    a0 += __shfl_xor(a0, 16); a0 += __shfl_xor(a0, 32);
    a1 += __shfl_xor(a1, 16); a1 += __shfl_xor(a1, 32);
    a2 += __shfl_xor(a2, 16); a2 += __shfl_xor(a2, 32);
    a3 += __shfl_xor(a3, 16); a3 += __shfl_xor(a3, 32);
    a4 += __shfl_xor(a4, 16); a4 += __shfl_xor(a4, 32);
    a5 += __shfl_xor(a5, 16); a5 += __shfl_xor(a5, 32);
    a6 += __shfl_xor(a6, 16); a6 += __shfl_xor(a6, 32);
    a7 += __shfl_xor(a7, 16); a7 += __shfl_xor(a7, 32);

    float denom = __shfl(myl, h2 * 8);
    float inv = 1.0f / fmaxf(denom, 1e-10f);

    if (lane < 16) {
        float4 o0 = make_float4(a0 * inv, a1 * inv, a2 * inv, a3 * inv);
        float4 o1 = make_float4(a4 * inv, a5 * inv, a6 * inv, a7 * inv);
        float4* op = (float4*)(out + (size_t)n * CHANNELS) + l16 * 2;
        op[0] = o0;
        op[1] = o1;
    }
}

// ---------------------------------------------------------------------------
extern "C" void kernel_launch(void* const* d_in, const int* in_sizes, int n_in,
                              void* d_out, int out_size, void* d_ws, size_t ws_size,
                              hipStream_t stream) {
    const float* x   = (const float*)d_in[0];
    const int*   ei  = (const int*)  d_in[1];   // (2, N_EDGES) row-major
    const float* att = (const float*)d_in[2];
    const int* src = ei;
    const int* dst = ei + N_EDGES;
    float* out = (float*)d_out;

    // Workspace layout (no memsets needed — bincnt zeroed by logit_kernel's
    // extra block; every other read location is written first):
    int*            bincnt_p = (int*)d_ws;                                  // NBINS*BPAD
    unsigned*       ebuf     = (unsigned*)(bincnt_p + (size_t)NBINS * BPAD);// NBINS*SEGCAP
    int*            cursor   = (int*)(ebuf + (size_t)NBINS * SEGCAP);       // N_NODES
    unsigned short* bucket   = (unsigned short*)(cursor + N_NODES);         // N_NODES*CAP
    float*          ls8      = (float*)(bucket + (size_t)N_NODES * CAP);    // N_NODES*HEADS
    float*          ld8      = ls8 + (size_t)N_NODES * HEADS;               // N_NODES*HEADS
    unsigned short* xb       = (unsigned short*)(ld8 + (size_t)N_NODES * HEADS);

    logit_kernel<<<LOGIT_VB + 1, 256, 0, stream>>>(x, att, ls8, ld8, xb, bincnt_p);
    binscatter_kernel<<<NCHUNK, 256, 0, stream>>>(src, dst, bincnt_p, ebuf);
    bucket_kernel<<<NBINS, 256, 0, stream>>>(ebuf, bincnt_p, cursor, bucket);
    fused_gat_kernel<<<(N_NODES + WPB - 1) / WPB, 64 * WPB, 0, stream>>>(
        xb, ls8, ld8, cursor, bucket, out);
}

// Round 4
// 136.434 us; speedup vs baseline: 1.0483x; 1.0483x over previous
//
#include <hip/hip_runtime.h>

#define N_NODES  50000
#define N_EDGES  600000
#define CHANNELS 128
#define HEADS    8
#define HEAD_DIM 16     // CHANNELS / HEADS
#define CAP      64     // per-node capacity; degrees ~ Poisson(12), max ~28

#define NBINS    1024   // dst bins; bin = dst*NBINS/N_NODES (~49 nodes/bin)
#define CHUNK_E  4096   // edges per chunk
#define NCHUNK   ((N_EDGES + CHUNK_E - 1) / CHUNK_E)     // 147
#define CAPC     24     // per-(chunk,bin) fixed slice; Poisson(4), P(>24)~1e-12
#define NPB      52     // max nodes per bin (49) padded

#define LOGIT_VB ((N_NODES * (CHANNELS / 8)) / 256)      // 3125 (8 channels/thread)
#define NW       4      // waves per aggregate block

// bf16 round-to-nearest-even of an fp32 bit pattern
__device__ __forceinline__ unsigned bf16rne(float f) {
    unsigned u = __float_as_uint(f);
    return (u + 0x7FFFu + ((u >> 16) & 1u)) >> 16;
}

// ---------------------------------------------------------------------------
// K1: logit sweep ∥ fixed-slice binscatter (disjoint block ranges, no
// ordering dependency, nothing pre-zeroed).
//  - blocks [0, NCHUNK): bin the chunk's 4096 edges.  Rank via LDS atomic
//    into the (chunk,bin) cell's FIXED slice ebuf[bin][chunk][CAPC].
//    No hist/scan/global-atomic allocation (R3 lesson: same-address global
//    atomic chains serialize ~40-100ns each on the home L2; R1 lesson:
//    never scatter sub-line stores across a large region — here stores
//    cluster ~4 per 96B cell).
//  - blocks [NCHUNK, NCHUNK+LOGIT_VB): per-node logit halves + bf16(x)
//    (8 channels/thread: 32B in, 16B packed-bf16 out).
// ---------------------------------------------------------------------------
__global__ void prep_kernel(const float* __restrict__ x,
                            const float* __restrict__ att,
                            const int*   __restrict__ src,
                            const int*   __restrict__ dst,
                            float*          __restrict__ ls8,
                            float*          __restrict__ ld8,
                            unsigned short* __restrict__ xb,
                            unsigned*       __restrict__ ebuf,
                            int*            __restrict__ cc) {
    int b = blockIdx.x;
    int t = threadIdx.x;
    if (b < NCHUNK) {
        __shared__ int lh[NBINS];                // rank counters, 4 KB
#pragma unroll
        for (int k = 0; k < NBINS / 256; ++k) lh[t + k * 256] = 0;
        __syncthreads();
        int base = b * CHUNK_E;
#pragma unroll 4
        for (int k = 0; k < CHUNK_E / 256; ++k) {
            int e = base + t + k * 256;
            if (e < N_EDGES) {
                int d = dst[e];
                int s = src[e];
                unsigned bin = ((unsigned)d * NBINS) / N_NODES;
                int r = atomicAdd(&lh[bin], 1);              // LDS atomic
                if (r < CAPC)
                    ebuf[((size_t)bin * NCHUNK + b) * CAPC + r] =
                        (unsigned)s | ((unsigned)d << 16);
            }
        }
        __syncthreads();
#pragma unroll
        for (int k = 0; k < NBINS / 256; ++k) {
            int bin = t + k * 256;
            cc[(size_t)bin * NCHUNK + b] = min(lh[bin], CAPC);   // bin-major for K2
        }
        return;
    }
    int gid = (b - NCHUNK) * 256 + t;            // (node, 8-channel slot)
    int n  = gid >> 4;                           // 16 slots per node
    int c8 = gid & 15;
    int h  = c8 >> 1;                            // 2 slots per head
    int j8 = c8 & 1;

    const float4* xp = (const float4*)x + (size_t)gid * 2;
    float4 v0 = xp[0], v1 = xp[1];

    // packed bf16 store: 8 channels -> uint4 (16B)
    uint4 pk;
    pk.x = bf16rne(v0.x) | (bf16rne(v0.y) << 16);
    pk.y = bf16rne(v0.z) | (bf16rne(v0.w) << 16);
    pk.z = bf16rne(v1.x) | (bf16rne(v1.y) << 16);
    pk.w = bf16rne(v1.z) | (bf16rne(v1.w) << 16);
    ((uint4*)xb)[gid] = pk;

    // att row = 32 floats = 8 float4s: [a_src(4), a_dst(4)]
    const float4* att4 = (const float4*)att;
    float4 as0 = att4[h * 8 + j8 * 2],     as1 = att4[h * 8 + j8 * 2 + 1];
    float4 ad0 = att4[h * 8 + 4 + j8 * 2], ad1 = att4[h * 8 + 5 + j8 * 2];
    float ts = v0.x*as0.x + v0.y*as0.y + v0.z*as0.z + v0.w*as0.w
             + v1.x*as1.x + v1.y*as1.y + v1.z*as1.z + v1.w*as1.w;
    float td = v0.x*ad0.x + v0.y*ad0.y + v0.z*ad0.z + v0.w*ad0.w
             + v1.x*ad1.x + v1.y*ad1.y + v1.z*ad1.z + v1.w*ad1.w;
    ts += __shfl_xor(ts, 1, 2);
    td += __shfl_xor(td, 1, 2);
    if (j8 == 0) {
        ls8[n * HEADS + h] = ts;
        ld8[n * HEADS + h] = td;
    }
}

// ---------------------------------------------------------------------------
// K2: bucket + fused GAT merged.  One block per bin (~49 nodes).
// Phase 1: sparse read of the bin's fixed-slice segment (slot < cc[c]),
//   LDS-atomic rank into per-node LDS rows (replaces the bucket kernel and
//   its 12.8MB global round-trip + cursor).
// Phase 2: per-wave node loop running the R11/R2-proven fused body:
//   Pass 1 (h=lane>>3, j=lane&7): logits in registers, 8-lane shuffle max
//     (clamped at 0 == reference's max(seg_max,0)), one exp per (edge,head)
//     -> LDS s_p, denominator reduced in-register.
//   Pass 2: 4 edges per wave-load — uint4/lane (16B), 16 lanes = one 256B
//     bf16 row; 4-slot statically-indexed uint4 window.  q[] must only be
//     indexed by compile-time constants (R12: dynamic indexing spills,
//     3.6x regression).
// rows[] slots >= cnt are uninitialized LDS: every access is `< cnt`-guarded
// or shfl-index-clamped, so garbage is never dereferenced.
// ---------------------------------------------------------------------------
__global__ void aggregate_kernel(const unsigned* __restrict__ ebuf,
                                 const int*      __restrict__ cc,
                                 const unsigned short* __restrict__ xb,
                                 const float* __restrict__ ls8,
                                 const float* __restrict__ ld8,
                                 float*       __restrict__ out) {
    __shared__ unsigned short rows[NPB * CAP];   // 6.5 KB
    __shared__ int   lcnt[NPB];
    __shared__ int   lcc[NCHUNK];                // 588 B
    __shared__ float s_p[NW * CAP * HEADS];      // 8 KB: per-wave softmax stage

    int b = blockIdx.x;
    int t = threadIdx.x;
    int n0 = (b * N_NODES + NBINS - 1) / NBINS;
    int n1 = ((b + 1) * N_NODES + NBINS - 1) / NBINS;
    int nn = n1 - n0;
    if (t < NPB) lcnt[t] = 0;
    if (t < NCHUNK) lcc[t] = cc[(size_t)b * NCHUNK + t];
    __syncthreads();

    // ---- phase 1: rank bin's edges into per-node LDS rows ----
    const unsigned* seg = ebuf + (size_t)b * NCHUNK * CAPC;
    for (int p = t; p < NCHUNK * CAPC; p += 256) {
        int c    = p / CAPC;                     // magic-mul, no HW div
        int slot = p - c * CAPC;
        if (slot < lcc[c]) {
            unsigned rec = seg[p];
            int s = (int)(rec & 0xFFFFu);
            int d = (int)(rec >> 16);
            int pos = atomicAdd(&lcnt[d - n0], 1);           // LDS atomic
            if (pos < CAP) rows[(d - n0) * CAP + pos] = (unsigned short)s;
        }
    }
    __syncthreads();

    // ---- phase 2: per-wave node loop, fused body ----
    int wave = t >> 6;
    int lane = t & 63;
    int h = lane >> 3;                           // pass-1 head
    int j = lane & 7;
    int r   = lane >> 4;                         // pass-2: which edge of quad (0..3)
    int l16 = lane & 15;                         // pass-2: channel octet
    int h2  = l16 >> 1;                          // pass-2 head
    float* sp = s_p + wave * (CAP * HEADS);

    for (int idx = wave; idx < nn; idx += NW) {
        int n = n0 + idx;
        int cnt_raw = lcnt[idx];
        int cnt = (cnt_raw > CAP) ? CAP : cnt_raw;
        int myidx = (int)rows[idx * CAP + lane];
        float ldst = ld8[n * HEADS + h];

        // ---- pass 1: logits in regs, per-head max, one exp per value ----
        float av[8];
        float mymax = -1e30f;
#pragma unroll
        for (int k = 0; k < 8; ++k) {
            int i = j + 8 * k;
            av[k] = -1e30f;
            if (i < cnt) {
                int   s  = __shfl(myidx, i);
                float lg = ls8[s * HEADS + h] + ldst;
                float a  = (lg >= 0.0f) ? lg : 0.2f * lg;   // LeakyReLU(0.2)
                av[k] = a;
                mymax = fmaxf(mymax, a);
            }
        }
#pragma unroll
        for (int o = 4; o >= 1; o >>= 1) mymax = fmaxf(mymax, __shfl_xor(mymax, o, 8));
        float m = fmaxf(mymax, 0.0f);            // reference clamps seg_max at 0

        float myl = 0.0f;
#pragma unroll
        for (int k = 0; k < 8; ++k) {
            int i = j + 8 * k;
            if (i < cnt) {
                float p = __expf(av[k] - m);
                sp[i * HEADS + h] = p;           // 2-way bank aliasing only
                myl += p;
            }
        }
#pragma unroll
        for (int o = 4; o >= 1; o >>= 1) myl += __shfl_xor(myl, o, 8);

        // ---- pass 2: weighted accumulate, 4 edges/load, 4 uint4 window ----
#define LO16(u) __uint_as_float((u) << 16)
#define HI16(u) __uint_as_float((u) & 0xFFFF0000u)
#define LP(kq) ( ((const uint4*)(xb + (size_t)__shfl(myidx, ((4*(kq)+r) < cnt) ? (4*(kq)+r) : 0) * CHANNELS))[l16] )
        uint4 q[4];
#pragma unroll
        for (int k = 0; k < 4; ++k) q[k] = LP(k);

        float a0 = 0.f, a1 = 0.f, a2 = 0.f, a3 = 0.f;
        float a4 = 0.f, a5 = 0.f, a6 = 0.f, a7 = 0.f;
        int nquad = (cnt + 3) >> 2;
        int k = 0;
        for (; k + 2 <= nquad; k += 2) {
#pragma unroll
            for (int u = 0; u < 2; ++u) {
                int e4 = 4 * (k + u) + r;
                float p = (e4 < cnt) ? sp[e4 * HEADS + h2] : 0.0f;
                uint4 qq = q[u];
                a0 += p * LO16(qq.x);
                a1 += p * HI16(qq.x);
                a2 += p * LO16(qq.y);
                a3 += p * HI16(qq.y);
                a4 += p * LO16(qq.z);
                a5 += p * HI16(qq.z);
                a6 += p * LO16(qq.w);
                a7 += p * HI16(qq.w);
            }
            q[0] = q[2]; q[1] = q[3];
            q[2] = LP(k + 4);
            q[3] = LP(k + 5);
        }
        for (; k < nquad; ++k) {                 // tail 0..1 quads
            int e4 = 4 * k + r;
            float p = (e4 < cnt) ? sp[e4 * HEADS + h2] : 0.0f;
            uint4 qq = q[0];
            a0 += p * LO16(qq.x);
            a1 += p * HI16(qq.x);
            a2 += p * LO16(qq.y);
            a3 += p * HI16(qq.y);
            a4 += p * LO16(qq.z);
            a5 += p * HI16(qq.z);
            a6 += p * LO16(qq.w);
            a7 += p * HI16(qq.w);
            q[0] = q[1]; q[1] = q[2]; q[2] = q[3];
        }
#undef LP
#undef LO16
#undef HI16

        a0 += __shfl_xor(a0, 16); a0 += __shfl_xor(a0, 32);
        a1 += __shfl_xor(a1, 16); a1 += __shfl_xor(a1, 32);
        a2 += __shfl_xor(a2, 16); a2 += __shfl_xor(a2, 32);
        a3 += __shfl_xor(a3, 16); a3 += __shfl_xor(a3, 32);
        a4 += __shfl_xor(a4, 16); a4 += __shfl_xor(a4, 32);
        a5 += __shfl_xor(a5, 16); a5 += __shfl_xor(a5, 32);
        a6 += __shfl_xor(a6, 16); a6 += __shfl_xor(a6, 32);
        a7 += __shfl_xor(a7, 16); a7 += __shfl_xor(a7, 32);

        float denom = __shfl(myl, h2 * 8);
        float inv = 1.0f / fmaxf(denom, 1e-10f);

        if (lane < 16) {
            float4 o0 = make_float4(a0 * inv, a1 * inv, a2 * inv, a3 * inv);
            float4 o1 = make_float4(a4 * inv, a5 * inv, a6 * inv, a7 * inv);
            float4* op = (float4*)(out + (size_t)n * CHANNELS) + l16 * 2;
            op[0] = o0;
            op[1] = o1;
        }
    }
}

// ---------------------------------------------------------------------------
extern "C" void kernel_launch(void* const* d_in, const int* in_sizes, int n_in,
                              void* d_out, int out_size, void* d_ws, size_t ws_size,
                              hipStream_t stream) {
    const float* x   = (const float*)d_in[0];
    const int*   ei  = (const int*)  d_in[1];   // (2, N_EDGES) row-major
    const float* att = (const float*)d_in[2];
    const int* src = ei;
    const int* dst = ei + N_EDGES;
    float* out = (float*)d_out;

    // Workspace layout (no memsets: ebuf garbage guarded by cc counts, rows
    // LDS garbage guarded by cnt; cc/ls8/ld8/xb fully written each iter):
    unsigned*       ebuf = (unsigned*)d_ws;                       // NBINS*NCHUNK*CAPC (14.5 MB)
    int*            cc   = (int*)(ebuf + (size_t)NBINS * NCHUNK * CAPC);   // NBINS*NCHUNK
    float*          ls8  = (float*)(cc + (size_t)NBINS * NCHUNK);          // N_NODES*HEADS
    float*          ld8  = ls8 + (size_t)N_NODES * HEADS;                  // N_NODES*HEADS
    unsigned short* xb   = (unsigned short*)(ld8 + (size_t)N_NODES * HEADS);

    prep_kernel<<<NCHUNK + LOGIT_VB, 256, 0, stream>>>(
        x, att, src, dst, ls8, ld8, xb, ebuf, cc);
    aggregate_kernel<<<NBINS, 256, 0, stream>>>(ebuf, cc, xb, ls8, ld8, out);
}